// Round 13
// baseline (92.996 us; speedup 1.0000x reference)
//
#include <hip/hip_runtime.h>

#define BB   128
#define DD   1024
#define RR   36
#define PP   8
#define NNEG 16
#define PRR  4

typedef __bf16 bf16x8 __attribute__((ext_vector_type(8)));
typedef float f32x4 __attribute__((ext_vector_type(4)));

// ws float layout: [0]=obj [1]=attr [2]=rel [3]=comp [4]=sent ; [16..400)=diag[3][128]
// byte 4096+: bf16 feat fragments [b][nt(3)][ks(32)][lane(64)][8]
#define WS_DIAG 16
#define WSF_OFF_BYTES 4096
#define WSF_PER_B (3 * 32 * 64 * 8)  // bf16 elems per b
#define WSF_BYTES ((size_t)WSF_OFF_BYTES + (size_t)BB * WSF_PER_B * 2)

// ---------------- prep: zero + diag + featcvt (grid (128,3) x 256) ----------
__global__ __launch_bounds__(256) void k_prep(const float* __restrict__ feat,
                                              const float* __restrict__ img,
                                              const float* __restrict__ sent,
                                              const float* __restrict__ comp,
                                              const float* __restrict__ rel,
                                              const int*   __restrict__ relidx,
                                              __bf16* __restrict__ wsf,
                                              float* __restrict__ ws) {
    const int b = blockIdx.x, nt = blockIdx.y, tid = threadIdx.x;
    if (b == 0 && nt == 0 && tid < 8) ws[tid] = 0.0f;

    const float* fb = feat + (size_t)b * RR * DD;
    __bf16* ob = wsf + (size_t)b * WSF_PER_B + (size_t)nt * 32 * 64 * 8;
    for (int i = tid; i < 32 * 64; i += 256) {
        const int ks = i >> 6, lane = i & 63;
        const int r = nt * 16 + (lane & 15);
        const int k0 = ks * 32 + (lane >> 4) * 8;
        bf16x8 w;
        if (r < RR) {
            float4 v0 = *reinterpret_cast<const float4*>(fb + (size_t)r * DD + k0);
            float4 v1 = *reinterpret_cast<const float4*>(fb + (size_t)r * DD + k0 + 4);
            w[0] = (__bf16)v0.x; w[1] = (__bf16)v0.y; w[2] = (__bf16)v0.z; w[3] = (__bf16)v0.w;
            w[4] = (__bf16)v1.x; w[5] = (__bf16)v1.y; w[6] = (__bf16)v1.z; w[7] = (__bf16)v1.w;
        } else {
#pragma unroll
            for (int j = 0; j < 8; ++j) w[j] = (__bf16)0.0f;
        }
        *reinterpret_cast<bf16x8*>(ob + (size_t)i * 8) = w;
    }

    if (tid < 64) {
        const int lane = tid;
        const float* x;
        if (nt == 0)      x = sent + (size_t)b * DD;
        else if (nt == 1) x = comp + (size_t)b * DD;
        else              x = rel + ((size_t)b * PRR + relidx[b]) * DD;
        const float* a = img + (size_t)b * DD;
        float acc = 0.0f;
#pragma unroll
        for (int k = 0; k < 4; ++k) {
            float4 va = *reinterpret_cast<const float4*>(a + lane * 4 + k * 256);
            float4 vb = *reinterpret_cast<const float4*>(x + lane * 4 + k * 256);
            acc += va.x * vb.x + va.y * vb.y + va.z * vb.z + va.w * vb.w;
        }
#pragma unroll
        for (int off = 32; off > 0; off >>= 1) acc += __shfl_down(acc, off);
        if (lane == 0) ws[WS_DIAG + nt * BB + b] = acc;
    }
}

// t-fused step: 13 operand regs -> 15 MFMAs (3 neg-srcs, 2 pos-srcs, 3 feat tiles)
__device__ __forceinline__ void compute_full(f32x4 nO0, f32x4 nO1, f32x4 nN0, f32x4 nN1,
                                             f32x4 nA0, f32x4 nA1, f32x4 pO0, f32x4 pO1,
                                             f32x4 pA0, f32x4 pA1,
                                             f32x4 fb0, f32x4 fb1, f32x4 fb2,
                                             f32x4 (&accn)[3][3], f32x4 (&accp)[2][3]) {
    bf16x8 aO, aN, aA, apO, apA;
#pragma unroll
    for (int j = 0; j < 4; ++j) {
        aO[j]  = (__bf16)nO0[j]; aO[j + 4]  = (__bf16)nO1[j];
        aN[j]  = (__bf16)nN0[j]; aN[j + 4]  = (__bf16)nN1[j];
        aA[j]  = (__bf16)nA0[j]; aA[j + 4]  = (__bf16)nA1[j];
        apO[j] = (__bf16)pO0[j]; apO[j + 4] = (__bf16)pO1[j];
        apA[j] = (__bf16)pA0[j]; apA[j + 4] = (__bf16)pA1[j];
    }
    bf16x8 b0 = __builtin_bit_cast(bf16x8, fb0);
    bf16x8 b1 = __builtin_bit_cast(bf16x8, fb1);
    bf16x8 b2 = __builtin_bit_cast(bf16x8, fb2);

    accn[0][0] = __builtin_amdgcn_mfma_f32_16x16x32_bf16(aO, b0, accn[0][0], 0, 0, 0);
    accn[0][1] = __builtin_amdgcn_mfma_f32_16x16x32_bf16(aO, b1, accn[0][1], 0, 0, 0);
    accn[0][2] = __builtin_amdgcn_mfma_f32_16x16x32_bf16(aO, b2, accn[0][2], 0, 0, 0);
    accn[1][0] = __builtin_amdgcn_mfma_f32_16x16x32_bf16(aN, b0, accn[1][0], 0, 0, 0);
    accn[1][1] = __builtin_amdgcn_mfma_f32_16x16x32_bf16(aN, b1, accn[1][1], 0, 0, 0);
    accn[1][2] = __builtin_amdgcn_mfma_f32_16x16x32_bf16(aN, b2, accn[1][2], 0, 0, 0);
    accn[2][0] = __builtin_amdgcn_mfma_f32_16x16x32_bf16(aA, b0, accn[2][0], 0, 0, 0);
    accn[2][1] = __builtin_amdgcn_mfma_f32_16x16x32_bf16(aA, b1, accn[2][1], 0, 0, 0);
    accn[2][2] = __builtin_amdgcn_mfma_f32_16x16x32_bf16(aA, b2, accn[2][2], 0, 0, 0);
    accp[0][0] = __builtin_amdgcn_mfma_f32_16x16x32_bf16(apO, b0, accp[0][0], 0, 0, 0);
    accp[0][1] = __builtin_amdgcn_mfma_f32_16x16x32_bf16(apO, b1, accp[0][1], 0, 0, 0);
    accp[0][2] = __builtin_amdgcn_mfma_f32_16x16x32_bf16(apO, b2, accp[0][2], 0, 0, 0);
    accp[1][0] = __builtin_amdgcn_mfma_f32_16x16x32_bf16(apA, b0, accp[1][0], 0, 0, 0);
    accp[1][1] = __builtin_amdgcn_mfma_f32_16x16x32_bf16(apA, b1, accp[1][1], 0, 0, 0);
    accp[1][2] = __builtin_amdgcn_mfma_f32_16x16x32_bf16(apA, b2, accp[1][2], 0, 0, 0);
}

// ---------------- mega (512 threads = 8 waves): t-fused local (x<8, split-K x8)
// + globalrel (8..11, 2 negs/wave) + contrastive (12..14, 32x16 tiles, y<32)
// SMEM overlay: local exchange uses stride-45 [64][45]; contrastive As[32][68]+Bs[16][68].
__global__ __launch_bounds__(512) void k_mega(const float* __restrict__ img,
                                              const float* __restrict__ sent,
                                              const float* __restrict__ comp,
                                              const float* __restrict__ obj,
                                              const float* __restrict__ attr,
                                              const float* __restrict__ nobj,
                                              const float* __restrict__ nattrn,
                                              const float* __restrict__ nattra,
                                              const float* __restrict__ rel,
                                              const float* __restrict__ nrel,
                                              const int*   __restrict__ relidx,
                                              const __bf16* __restrict__ wsf,
                                              float* __restrict__ ws) {
    const int x = blockIdx.x, y = blockIdx.y;
    const int tid = threadIdx.x;

    __shared__ __attribute__((aligned(16))) float SMEM[64 * 52];
    __shared__ float comm[12];

    if (x < 8) {
        // ======== t-fused local_loss: p = x, b = y; 8 waves = 8 K-eighths ====
        const int p = x, b = y;
        const int kh = tid >> 6;              // K-eighth (0..7)
        const int lane = tid & 63;
        const int lrow = lane & 15;
        const int kgq = lane >> 4;
        const int ksbase = kh * 4;            // 4 ks-steps of 32 per eighth

        const float* posO = obj    + ((size_t)b * PP + p) * DD + kgq * 8;
        const float* posA = attr   + ((size_t)b * PP + p) * DD + kgq * 8;
        const float* negO = nobj   + ((size_t)(b * PP + p) * NNEG + lrow) * DD + kgq * 8;
        const float* negN = nattrn + ((size_t)(b * PP + p) * NNEG + lrow) * DD + kgq * 8;
        const float* negA = nattra + ((size_t)(b * PP + p) * NNEG + lrow) * DD + kgq * 8;
        const __bf16* wfb = wsf + (size_t)b * WSF_PER_B + (size_t)lane * 8;

        f32x4 accn[3][3], accp[2][3];
#pragma unroll
        for (int t = 0; t < 3; ++t)
#pragma unroll
            for (int nt = 0; nt < 3; ++nt) accn[t][nt] = (f32x4){0.f, 0.f, 0.f, 0.f};
#pragma unroll
        for (int s = 0; s < 2; ++s)
#pragma unroll
            for (int nt = 0; nt < 3; ++nt) accp[s][nt] = (f32x4){0.f, 0.f, 0.f, 0.f};

        // 2-deep rotating buffer sets, individually named.
        f32x4 nO0_0, nO1_0, nN0_0, nN1_0, nA0_0, nA1_0, pO0_0, pO1_0, pA0_0, pA1_0,
              fB0_0, fB1_0, fB2_0;
        f32x4 nO0_1, nO1_1, nN0_1, nN1_1, nA0_1, nA1_1, pO0_1, pO1_1, pA0_1, pA1_1,
              fB0_1, fB1_1, fB2_1;

#define ISSUE(KS, B)                                                                    \
    {                                                                                   \
        const float* nO_ = negO + (ksbase + (KS)) * 32;                                 \
        const float* nN_ = negN + (ksbase + (KS)) * 32;                                 \
        const float* nA_ = negA + (ksbase + (KS)) * 32;                                 \
        const float* pO_ = posO + (ksbase + (KS)) * 32;                                 \
        const float* pA_ = posA + (ksbase + (KS)) * 32;                                 \
        const __bf16* g0_ = wfb + (size_t)(0 * 32 + ksbase + (KS)) * 512;               \
        const __bf16* g1_ = wfb + (size_t)(1 * 32 + ksbase + (KS)) * 512;               \
        const __bf16* g2_ = wfb + (size_t)(2 * 32 + ksbase + (KS)) * 512;               \
        asm volatile("global_load_dwordx4 %0, %1, off" : "=v"(nO0_##B) : "v"(nO_));     \
        asm volatile("global_load_dwordx4 %0, %1, off offset:16"                        \
                     : "=v"(nO1_##B) : "v"(nO_));                                       \
        asm volatile("global_load_dwordx4 %0, %1, off" : "=v"(nN0_##B) : "v"(nN_));     \
        asm volatile("global_load_dwordx4 %0, %1, off offset:16"                        \
                     : "=v"(nN1_##B) : "v"(nN_));                                       \
        asm volatile("global_load_dwordx4 %0, %1, off" : "=v"(nA0_##B) : "v"(nA_));     \
        asm volatile("global_load_dwordx4 %0, %1, off offset:16"                        \
                     : "=v"(nA1_##B) : "v"(nA_));                                       \
        asm volatile("global_load_dwordx4 %0, %1, off" : "=v"(pO0_##B) : "v"(pO_));     \
        asm volatile("global_load_dwordx4 %0, %1, off offset:16"                        \
                     : "=v"(pO1_##B) : "v"(pO_));                                       \
        asm volatile("global_load_dwordx4 %0, %1, off" : "=v"(pA0_##B) : "v"(pA_));     \
        asm volatile("global_load_dwordx4 %0, %1, off offset:16"                        \
                     : "=v"(pA1_##B) : "v"(pA_));                                       \
        asm volatile("global_load_dwordx4 %0, %1, off" : "=v"(fB0_##B) : "v"(g0_));     \
        asm volatile("global_load_dwordx4 %0, %1, off" : "=v"(fB1_##B) : "v"(g1_));     \
        asm volatile("global_load_dwordx4 %0, %1, off" : "=v"(fB2_##B) : "v"(g2_));     \
    }

#define WAITV(N)                                          \
    asm volatile("s_waitcnt vmcnt(" #N ")" ::: "memory"); \
    __builtin_amdgcn_sched_barrier(0);

#define COMPUTE(B) compute_full(nO0_##B, nO1_##B, nN0_##B, nN1_##B, nA0_##B, nA1_##B,   \
                                pO0_##B, pO1_##B, pA0_##B, pA1_##B,                     \
                                fB0_##B, fB1_##B, fB2_##B, accn, accp);

        WAITV(0)
        ISSUE(0, 0)
        ISSUE(1, 1) WAITV(13) COMPUTE(0)
        ISSUE(2, 0) WAITV(13) COMPUTE(1)
        ISSUE(3, 1) WAITV(13) COMPUTE(0)
        WAITV(0)  COMPUTE(1)

#undef ISSUE
#undef WAITV
#undef COMPUTE

        // staged cross-eighth combine via single SMEM buffer, stride 45:
        // phase q: wave q publishes 42 floats/lane, wave 0 accumulates.
#define XW(L, J) SMEM[(L) * 45 + (J)]
        for (int q = 1; q <= 7; ++q) {
            if (kh == q) {
#pragma unroll
                for (int t = 0; t < 3; ++t)
#pragma unroll
                    for (int nt = 0; nt < 3; ++nt) {
                        XW(lane, t * 12 + nt * 4 + 0) = accn[t][nt][0];
                        XW(lane, t * 12 + nt * 4 + 1) = accn[t][nt][1];
                        XW(lane, t * 12 + nt * 4 + 2) = accn[t][nt][2];
                        XW(lane, t * 12 + nt * 4 + 3) = accn[t][nt][3];
                    }
#pragma unroll
                for (int s = 0; s < 2; ++s)
#pragma unroll
                    for (int nt = 0; nt < 3; ++nt)
                        XW(lane, 36 + s * 3 + nt) = accp[s][nt][0];
            }
            __syncthreads();
            if (kh == 0) {
#pragma unroll
                for (int t = 0; t < 3; ++t)
#pragma unroll
                    for (int nt = 0; nt < 3; ++nt) {
                        accn[t][nt][0] += XW(lane, t * 12 + nt * 4 + 0);
                        accn[t][nt][1] += XW(lane, t * 12 + nt * 4 + 1);
                        accn[t][nt][2] += XW(lane, t * 12 + nt * 4 + 2);
                        accn[t][nt][3] += XW(lane, t * 12 + nt * 4 + 3);
                    }
#pragma unroll
                for (int s = 0; s < 2; ++s)
#pragma unroll
                    for (int nt = 0; nt < 3; ++nt)
                        accp[s][nt][0] += XW(lane, 36 + s * 3 + nt);
            }
            __syncthreads();
        }
#undef XW

        if (kh == 0) {
            // row-max over the 16 negs per (t, nt)
            float mt[3][3];
#pragma unroll
            for (int t = 0; t < 3; ++t)
#pragma unroll
                for (int nt = 0; nt < 3; ++nt) {
                    f32x4 a = accn[t][nt];
                    float m = fmaxf(fmaxf(a[0], a[1]), fmaxf(a[2], a[3]));
                    m = fmaxf(m, __shfl_xor(m, 16));
                    m = fmaxf(m, __shfl_xor(m, 32));
                    mt[t][nt] = m;
                }
            float s0[3], s1[3];
#pragma unroll
            for (int nt = 0; nt < 3; ++nt) {
                s0[nt] = accp[0][nt][0];
                s1[nt] = accp[1][nt][0];
            }

            float mx0 = -1e30f, mx1 = -1e30f;
#pragma unroll
            for (int nt = 0; nt < 3; ++nt)
                if (nt * 16 + lrow < RR) {
                    mx0 = fmaxf(mx0, s0[nt]);
                    mx1 = fmaxf(mx1, s1[nt]);
                }
#pragma unroll
            for (int off = 1; off < 16; off <<= 1) {
                mx0 = fmaxf(mx0, __shfl_xor(mx0, off));
                mx1 = fmaxf(mx1, __shfl_xor(mx1, off));
            }
            float den0 = 0.f, num0 = 0.f, den1 = 0.f, num1 = 0.f;
#pragma unroll
            for (int nt = 0; nt < 3; ++nt)
                if (nt * 16 + lrow < RR) {
                    float e0 = __expf(s0[nt] - mx0);
                    den0 += e0;
                    num0 += e0 * fmaxf(mt[0][nt] - s0[nt], 0.0f);
                    float e1 = __expf(s1[nt] - mx1);
                    den1 += e1;
                    num1 += e1 * (fmaxf(mt[1][nt] - s1[nt], 0.0f) +
                                  fmaxf(mt[2][nt] - s1[nt], 0.0f));
                }
#pragma unroll
            for (int off = 1; off < 16; off <<= 1) {
                den0 += __shfl_xor(den0, off);
                num0 += __shfl_xor(num0, off);
                den1 += __shfl_xor(den1, off);
                num1 += __shfl_xor(num1, off);
            }
            if (lane == 0) {
                atomicAdd(&ws[0], num0 / den0);
                atomicAdd(&ws[1], num1 / den1);
            }
        }
    } else if (x < 12) {
        // ======== global_loss(rel): p = x-8, b = y; 8 waves x 2 negs ========
        const int p = x - 8, b = y;
        const int wv = tid >> 6, lane = tid & 63;
        const float* a = img + (size_t)b * DD;
        float4 ir[4];
#pragma unroll
        for (int k = 0; k < 4; ++k)
            ir[k] = *reinterpret_cast<const float4*>(a + lane * 4 + k * 256);

        auto dotv = [&](const float* __restrict__ v) -> float {
            float acc = 0.0f;
#pragma unroll
            for (int k = 0; k < 4; ++k) {
                float4 w = *reinterpret_cast<const float4*>(v + lane * 4 + k * 256);
                acc += ir[k].x * w.x + ir[k].y * w.y + ir[k].z * w.z + ir[k].w * w.w;
            }
#pragma unroll
            for (int off = 32; off > 0; off >>= 1) acc += __shfl_xor(acc, off);
            return acc;
        };

        if (wv == 0) {
            float pos = dotv(rel + ((size_t)b * PRR + p) * DD);
            if (lane == 0) comm[8] = pos;
        }
        const float* nb = nrel + ((size_t)b * PRR + p) * NNEG * DD;
        float m = -1e30f;
#pragma unroll
        for (int j = 0; j < 2; ++j)
            m = fmaxf(m, dotv(nb + (size_t)(wv * 2 + j) * DD));
        if (lane == 0) comm[wv] = m;
        __syncthreads();
        if (tid == 0) {
            float mx = comm[0];
#pragma unroll
            for (int q = 1; q < 8; ++q) mx = fmaxf(mx, comm[q]);
            atomicAdd(&ws[2], fmaxf(mx - comm[8], 0.0f));
        }
    } else {
        // ======== contrastive: t = x-12; y<32 => 32x16 tile (y>>3, y&7) =====
        if (y >= 32) return;
        const int t = x - 12;
        const int i0 = (y >> 3) * 32, j0 = (y & 7) * 16;
        const int ty = tid >> 4, tx = tid & 15;   // ty 0..31, tx 0..15

        float (*As)[68] = reinterpret_cast<float(*)[68]>(SMEM);
        float (*Bs)[68] = reinterpret_cast<float(*)[68]>(SMEM + 32 * 68);

        const int j_row = j0 + (ty & 15);
        const float* brow;
        if (t == 0)      brow = sent + (size_t)j_row * DD;
        else if (t == 1) brow = comp + (size_t)j_row * DD;
        else             brow = rel + ((size_t)j_row * PRR + relidx[j_row]) * DD;
        const float* arow = img + (size_t)(i0 + ty) * DD;

        float acc = 0.0f;
        for (int kc = 0; kc < DD; kc += 64) {
            __syncthreads();
            float4 va = *reinterpret_cast<const float4*>(arow + kc + tx * 4);
            *reinterpret_cast<float4*>(&As[ty][tx * 4]) = va;
            if (ty < 16) {
                float4 vb = *reinterpret_cast<const float4*>(brow + kc + tx * 4);
                *reinterpret_cast<float4*>(&Bs[ty][tx * 4]) = vb;
            }
            __syncthreads();
#pragma unroll 8
            for (int d = 0; d < 64; ++d)
                acc += As[ty][d] * Bs[tx][d];
        }

        const int i = i0 + ty, j = j0 + tx;
        const float diag_i = ws[WS_DIAG + t * BB + i];
        const float diag_j = ws[WS_DIAG + t * BB + j];
        float contrib = 0.0f;
        if (i != j) {
            contrib = fmaxf(acc - diag_i, 0.0f);             // cost_s
            if (t < 2) contrib += fmaxf(acc - diag_j, 0.0f); // cost_im (not for rel)
        }
#pragma unroll
        for (int off = 32; off > 0; off >>= 1) contrib += __shfl_down(contrib, off);
        if ((tid & 63) == 0) comm[tid >> 6] = contrib;
        __syncthreads();
        if (tid == 0) {
            float s = 0.0f;
#pragma unroll
            for (int q = 0; q < 8; ++q) s += comm[q];
            const int slot = (t == 0) ? 4 : (t == 1) ? 3 : 2;  // sent/comp/rel
            atomicAdd(&ws[slot], s);
        }
    }
}

// ---------------- fallback kernels (no-wsf path) ----------------------------
__global__ __launch_bounds__(64) void k_zero(float* __restrict__ ws) {
    int t = threadIdx.x;
    if (t < 8) ws[t] = 0.0f;
}

__global__ __launch_bounds__(64) void k_diag(const float* __restrict__ img,
                                             const float* __restrict__ sent,
                                             const float* __restrict__ comp,
                                             const float* __restrict__ rel,
                                             const int*   __restrict__ relidx,
                                             float* __restrict__ ws) {
    const int i = blockIdx.x, t = blockIdx.y, lane = threadIdx.x;
    const float* x;
    if (t == 0)      x = sent + (size_t)i * DD;
    else if (t == 1) x = comp + (size_t)i * DD;
    else             x = rel + ((size_t)i * PRR + relidx[i]) * DD;
    const float* a = img + (size_t)i * DD;
    float acc = 0.0f;
#pragma unroll
    for (int k = 0; k < 4; ++k) {
        float4 va = *reinterpret_cast<const float4*>(a + lane * 4 + k * 256);
        float4 vb = *reinterpret_cast<const float4*>(x + lane * 4 + k * 256);
        acc += va.x * vb.x + va.y * vb.y + va.z * vb.z + va.w * vb.w;
    }
#pragma unroll
    for (int off = 32; off > 0; off >>= 1) acc += __shfl_down(acc, off);
    if (lane == 0) ws[WS_DIAG + t * BB + i] = acc;
}

__global__ __launch_bounds__(256) void k_contrastive(const float* __restrict__ img,
                                                     const float* __restrict__ sent,
                                                     const float* __restrict__ comp,
                                                     const float* __restrict__ rel,
                                                     const int*   __restrict__ relidx,
                                                     float* __restrict__ ws) {
    const int t  = blockIdx.z;
    const int i0 = blockIdx.y * 16, j0 = blockIdx.x * 16;
    const int tid = threadIdx.x, ty = tid >> 4, tx = tid & 15;
    __shared__ float As[16][68];
    __shared__ float Bs[16][68];
    __shared__ float red[4];

    const int j_row = j0 + ty;
    const float* brow;
    if (t == 0)      brow = sent + (size_t)j_row * DD;
    else if (t == 1) brow = comp + (size_t)j_row * DD;
    else             brow = rel + ((size_t)j_row * PRR + relidx[j_row]) * DD;
    const float* arow = img + (size_t)(i0 + ty) * DD;

    float acc = 0.0f;
    for (int kc = 0; kc < DD; kc += 64) {
        __syncthreads();
        float4 va = *reinterpret_cast<const float4*>(arow + kc + tx * 4);
        float4 vb = *reinterpret_cast<const float4*>(brow + kc + tx * 4);
        *reinterpret_cast<float4*>(&As[ty][tx * 4]) = va;
        *reinterpret_cast<float4*>(&Bs[ty][tx * 4]) = vb;
        __syncthreads();
#pragma unroll 8
        for (int d = 0; d < 64; ++d)
            acc += As[ty][d] * Bs[tx][d];
    }

    const int i = i0 + ty, j = j0 + tx;
    const float diag_i = ws[WS_DIAG + t * BB + i];
    const float diag_j = ws[WS_DIAG + t * BB + j];
    float contrib = 0.0f;
    if (i != j) {
        contrib = fmaxf(acc - diag_i, 0.0f);
        if (t < 2) contrib += fmaxf(acc - diag_j, 0.0f);
    }
#pragma unroll
    for (int off = 32; off > 0; off >>= 1) contrib += __shfl_down(contrib, off);
    if ((tid & 63) == 0) red[tid >> 6] = contrib;
    __syncthreads();
    if (tid == 0) {
        const int slot = (t == 0) ? 4 : (t == 1) ? 3 : 2;
        atomicAdd(&ws[slot], red[0] + red[1] + red[2] + red[3]);
    }
}

__global__ __launch_bounds__(64) void k_globalrel(const float* __restrict__ img,
                                                  const float* __restrict__ rel,
                                                  const float* __restrict__ negrel,
                                                  float* __restrict__ ws) {
    const int blk = blockIdx.x, b = blk >> 2, p = blk & 3;
    const int lane = threadIdx.x;
    const float* a = img + (size_t)b * DD;
    float4 ir[4];
#pragma unroll
    for (int k = 0; k < 4; ++k)
        ir[k] = *reinterpret_cast<const float4*>(a + lane * 4 + k * 256);

    auto dotv = [&](const float* __restrict__ v) -> float {
        float acc = 0.0f;
#pragma unroll
        for (int k = 0; k < 4; ++k) {
            float4 w = *reinterpret_cast<const float4*>(v + lane * 4 + k * 256);
            acc += ir[k].x * w.x + ir[k].y * w.y + ir[k].z * w.z + ir[k].w * w.w;
        }
#pragma unroll
        for (int off = 32; off > 0; off >>= 1) acc += __shfl_xor(acc, off);
        return acc;
    };

    float pos = dotv(rel + ((size_t)b * PRR + p) * DD);
    float mx = -1e30f;
    const float* nb = negrel + ((size_t)b * PRR + p) * NNEG * DD;
    for (int n = 0; n < NNEG; ++n) mx = fmaxf(mx, dotv(nb + (size_t)n * DD));
    if (lane == 0) atomicAdd(&ws[2], fmaxf(mx - pos, 0.0f));
}

__global__ __launch_bounds__(256) void k_local6f(const float* __restrict__ feat,
                                                 const float* __restrict__ obj,
                                                 const float* __restrict__ attr,
                                                 const float* __restrict__ nobj,
                                                 const float* __restrict__ nattrn,
                                                 const float* __restrict__ nattra,
                                                 float* __restrict__ ws) {
    const int t = blockIdx.x;
    const int b = blockIdx.y;
    const int p = blockIdx.z;
    const int tid = threadIdx.x;
    const int kh = tid >> 6;
    const int lane = tid & 63;
    const int lrow = lane & 15;
    const int kgq = lane >> 4;
    const int ksbase = kh * 8;

    const float* pos = (t == 0) ? obj : attr;
    const float* neg = (t == 0) ? nobj : (t == 1) ? nattrn : nattra;
    const float* posb = pos + ((size_t)b * PP + p) * DD + kgq * 8;
    const float* negb = neg + ((size_t)(b * PP + p) * NNEG + lrow) * DD + kgq * 8;
    const float* fb   = feat + (size_t)b * RR * DD;

    f32x4 accn[3], accp[3];
#pragma unroll
    for (int nt = 0; nt < 3; ++nt) {
        accn[nt] = (f32x4){0.f, 0.f, 0.f, 0.f};
        accp[nt] = (f32x4){0.f, 0.f, 0.f, 0.f};
    }

    for (int ksl = 0; ksl < 8; ++ksl) {
        const int ks = ksbase + ksl;
        const float* np = negb + ks * 32;
        float4 n0 = *reinterpret_cast<const float4*>(np);
        float4 n1 = *reinterpret_cast<const float4*>(np + 4);
        const float* pq = posb + ks * 32;
        float4 p0 = *reinterpret_cast<const float4*>(pq);
        float4 p1 = *reinterpret_cast<const float4*>(pq + 4);
        bf16x8 an, ap;
        an[0] = (__bf16)n0.x; an[1] = (__bf16)n0.y; an[2] = (__bf16)n0.z; an[3] = (__bf16)n0.w;
        an[4] = (__bf16)n1.x; an[5] = (__bf16)n1.y; an[6] = (__bf16)n1.z; an[7] = (__bf16)n1.w;
        ap[0] = (__bf16)p0.x; ap[1] = (__bf16)p0.y; ap[2] = (__bf16)p0.z; ap[3] = (__bf16)p0.w;
        ap[4] = (__bf16)p1.x; ap[5] = (__bf16)p1.y; ap[6] = (__bf16)p1.z; ap[7] = (__bf16)p1.w;
#pragma unroll
        for (int nt = 0; nt < 3; ++nt) {
            bf16x8 bt;
            const int r = nt * 16 + lrow;
            if (r < RR) {
                const float* fp = fb + (size_t)r * DD + ks * 32 + kgq * 8;
                float4 v0 = *reinterpret_cast<const float4*>(fp);
                float4 v1 = *reinterpret_cast<const float4*>(fp + 4);
                bt[0] = (__bf16)v0.x; bt[1] = (__bf16)v0.y; bt[2] = (__bf16)v0.z; bt[3] = (__bf16)v0.w;
                bt[4] = (__bf16)v1.x; bt[5] = (__bf16)v1.y; bt[6] = (__bf16)v1.z; bt[7] = (__bf16)v1.w;
            } else {
#pragma unroll
                for (int j = 0; j < 8; ++j) bt[j] = (__bf16)0.0f;
            }
            accn[nt] = __builtin_amdgcn_mfma_f32_16x16x32_bf16(an, bt, accn[nt], 0, 0, 0);
            accp[nt] = __builtin_amdgcn_mfma_f32_16x16x32_bf16(ap, bt, accp[nt], 0, 0, 0);
        }
    }

    __shared__ float X[3][64][17];
    if (kh != 0) {
#pragma unroll
        for (int nt = 0; nt < 3; ++nt) {
            X[kh - 1][lane][nt * 4 + 0] = accn[nt][0];
            X[kh - 1][lane][nt * 4 + 1] = accn[nt][1];
            X[kh - 1][lane][nt * 4 + 2] = accn[nt][2];
            X[kh - 1][lane][nt * 4 + 3] = accn[nt][3];
            X[kh - 1][lane][12 + nt]    = accp[nt][0];
        }
    }
    __syncthreads();
    if (kh == 0) {
#pragma unroll
        for (int q = 0; q < 3; ++q)
#pragma unroll
            for (int nt = 0; nt < 3; ++nt) {
                accn[nt][0] += X[q][lane][nt * 4 + 0];
                accn[nt][1] += X[q][lane][nt * 4 + 1];
                accn[nt][2] += X[q][lane][nt * 4 + 2];
                accn[nt][3] += X[q][lane][nt * 4 + 3];
                accp[nt][0] += X[q][lane][12 + nt];
            }
        float s3[3], h3[3];
#pragma unroll
        for (int nt = 0; nt < 3; ++nt) {
            f32x4 a = accn[nt];
            float m = fmaxf(fmaxf(a[0], a[1]), fmaxf(a[2], a[3]));
            m = fmaxf(m, __shfl_xor(m, 16));
            m = fmaxf(m, __shfl_xor(m, 32));
            s3[nt] = accp[nt][0];
            h3[nt] = fmaxf(m - s3[nt], 0.0f);
        }
        float mx = -1e30f;
#pragma unroll
        for (int nt = 0; nt < 3; ++nt)
            if (nt * 16 + lrow < RR) mx = fmaxf(mx, s3[nt]);
#pragma unroll
        for (int off = 1; off < 16; off <<= 1) mx = fmaxf(mx, __shfl_xor(mx, off));
        float den = 0.0f, num = 0.0f;
#pragma unroll
        for (int nt = 0; nt < 3; ++nt)
            if (nt * 16 + lrow < RR) {
                float e = __expf(s3[nt] - mx);
                den += e;
                num += e * h3[nt];
            }
#pragma unroll
        for (int off = 1; off < 16; off <<= 1) {
            den += __shfl_xor(den, off);
            num += __shfl_xor(num, off);
        }
        if (lane == 0)
            atomicAdd(&ws[(t == 0) ? 0 : 1], num / den);
    }
}

__global__ __launch_bounds__(64) void k_final(const float* __restrict__ ws,
                                              float* __restrict__ out) {
    if (threadIdx.x == 0) {
        const float obj = ws[0], attr = ws[1], rel = ws[2], comp = ws[3], sent = ws[4];
        out[0] = sent + 0.5f * comp + 0.5f * rel + 0.5f * attr + 0.5f * obj;
        out[1] = obj;
        out[2] = attr;
        out[3] = rel;
        out[4] = comp;
        out[5] = sent;
    }
}

extern "C" void kernel_launch(void* const* d_in, const int* in_sizes, int n_in,
                              void* d_out, int out_size, void* d_ws, size_t ws_size,
                              hipStream_t stream) {
    const float* img    = (const float*)d_in[0];
    const float* sent   = (const float*)d_in[1];
    const float* comp   = (const float*)d_in[2];
    const float* feat   = (const float*)d_in[3];
    const float* obj    = (const float*)d_in[4];
    const float* nobj   = (const float*)d_in[5];
    const float* attr   = (const float*)d_in[6];
    const float* nattrn = (const float*)d_in[7];
    const float* nattra = (const float*)d_in[8];
    const float* rel    = (const float*)d_in[9];
    const float* nrel   = (const float*)d_in[10];
    const int*   relidx = (const int*)d_in[11];
    float* ws  = (float*)d_ws;
    float* out = (float*)d_out;
    __bf16* wsf = (__bf16*)((char*)d_ws + WSF_OFF_BYTES);

    const bool usewsf = (ws_size >= WSF_BYTES);

    if (usewsf) {
        k_prep<<<dim3(BB, 3), dim3(256), 0, stream>>>(feat, img, sent, comp, rel, relidx,
                                                      wsf, ws);
        k_mega<<<dim3(15, BB), dim3(512), 0, stream>>>(img, sent, comp, obj, attr, nobj,
                                                       nattrn, nattra, rel, nrel, relidx,
                                                       wsf, ws);
        k_final<<<dim3(1), dim3(64), 0, stream>>>(ws, out);
    } else {
        k_zero<<<dim3(1), dim3(64), 0, stream>>>(ws);
        k_diag<<<dim3(BB, 3), dim3(64), 0, stream>>>(img, sent, comp, rel, relidx, ws);
        k_contrastive<<<dim3(8, 8, 3), dim3(256), 0, stream>>>(img, sent, comp, rel, relidx, ws);
        k_globalrel<<<dim3(BB * PRR), dim3(64), 0, stream>>>(img, rel, nrel, ws);
        k_local6f<<<dim3(3, BB, PP), dim3(256), 0, stream>>>(feat, obj, attr, nobj, nattrn,
                                                             nattra, ws);
        k_final<<<dim3(1), dim3(64), 0, stream>>>(ws, out);
    }
}

// Round 14
// 81.753 us; speedup vs baseline: 1.1375x; 1.1375x over previous
//
#include <hip/hip_runtime.h>

#define BB   128
#define DD   1024
#define RR   36
#define PP   8
#define NNEG 16
#define PRR  4

typedef __bf16 bf16x8 __attribute__((ext_vector_type(8)));
typedef float f32x4 __attribute__((ext_vector_type(4)));

// ws float layout: [0]=obj [1]=attr [2]=rel [3]=comp [4]=sent ; [16..400)=diag[3][128]
// byte 4096+: bf16 feat fragments [b][nt(3)][ks(32)][lane(64)][8]
#define WS_DIAG 16
#define WSF_OFF_BYTES 4096
#define WSF_PER_B (3 * 32 * 64 * 8)  // bf16 elems per b
#define WSF_BYTES ((size_t)WSF_OFF_BYTES + (size_t)BB * WSF_PER_B * 2)

// ---------------- prep: zero + diag + featcvt (grid (128,3) x 256) ----------
__global__ __launch_bounds__(256) void k_prep(const float* __restrict__ feat,
                                              const float* __restrict__ img,
                                              const float* __restrict__ sent,
                                              const float* __restrict__ comp,
                                              const float* __restrict__ rel,
                                              const int*   __restrict__ relidx,
                                              __bf16* __restrict__ wsf,
                                              float* __restrict__ ws) {
    const int b = blockIdx.x, nt = blockIdx.y, tid = threadIdx.x;
    if (b == 0 && nt == 0 && tid < 8) ws[tid] = 0.0f;

    const float* fb = feat + (size_t)b * RR * DD;
    __bf16* ob = wsf + (size_t)b * WSF_PER_B + (size_t)nt * 32 * 64 * 8;
    for (int i = tid; i < 32 * 64; i += 256) {
        const int ks = i >> 6, lane = i & 63;
        const int r = nt * 16 + (lane & 15);
        const int k0 = ks * 32 + (lane >> 4) * 8;
        bf16x8 w;
        if (r < RR) {
            float4 v0 = *reinterpret_cast<const float4*>(fb + (size_t)r * DD + k0);
            float4 v1 = *reinterpret_cast<const float4*>(fb + (size_t)r * DD + k0 + 4);
            w[0] = (__bf16)v0.x; w[1] = (__bf16)v0.y; w[2] = (__bf16)v0.z; w[3] = (__bf16)v0.w;
            w[4] = (__bf16)v1.x; w[5] = (__bf16)v1.y; w[6] = (__bf16)v1.z; w[7] = (__bf16)v1.w;
        } else {
#pragma unroll
            for (int j = 0; j < 8; ++j) w[j] = (__bf16)0.0f;
        }
        *reinterpret_cast<bf16x8*>(ob + (size_t)i * 8) = w;
    }

    if (tid < 64) {
        const int lane = tid;
        const float* x;
        if (nt == 0)      x = sent + (size_t)b * DD;
        else if (nt == 1) x = comp + (size_t)b * DD;
        else              x = rel + ((size_t)b * PRR + relidx[b]) * DD;
        const float* a = img + (size_t)b * DD;
        float acc = 0.0f;
#pragma unroll
        for (int k = 0; k < 4; ++k) {
            float4 va = *reinterpret_cast<const float4*>(a + lane * 4 + k * 256);
            float4 vb = *reinterpret_cast<const float4*>(x + lane * 4 + k * 256);
            acc += va.x * vb.x + va.y * vb.y + va.z * vb.z + va.w * vb.w;
        }
#pragma unroll
        for (int off = 32; off > 0; off >>= 1) acc += __shfl_down(acc, off);
        if (lane == 0) ws[WS_DIAG + nt * BB + b] = acc;
    }
}

// t-fused step: 13 operand regs -> 15 MFMAs (3 neg-srcs, 2 pos-srcs, 3 feat tiles)
__device__ __forceinline__ void compute_full(f32x4 nO0, f32x4 nO1, f32x4 nN0, f32x4 nN1,
                                             f32x4 nA0, f32x4 nA1, f32x4 pO0, f32x4 pO1,
                                             f32x4 pA0, f32x4 pA1,
                                             f32x4 fb0, f32x4 fb1, f32x4 fb2,
                                             f32x4 (&accn)[3][3], f32x4 (&accp)[2][3]) {
    bf16x8 aO, aN, aA, apO, apA;
#pragma unroll
    for (int j = 0; j < 4; ++j) {
        aO[j]  = (__bf16)nO0[j]; aO[j + 4]  = (__bf16)nO1[j];
        aN[j]  = (__bf16)nN0[j]; aN[j + 4]  = (__bf16)nN1[j];
        aA[j]  = (__bf16)nA0[j]; aA[j + 4]  = (__bf16)nA1[j];
        apO[j] = (__bf16)pO0[j]; apO[j + 4] = (__bf16)pO1[j];
        apA[j] = (__bf16)pA0[j]; apA[j + 4] = (__bf16)pA1[j];
    }
    bf16x8 b0 = __builtin_bit_cast(bf16x8, fb0);
    bf16x8 b1 = __builtin_bit_cast(bf16x8, fb1);
    bf16x8 b2 = __builtin_bit_cast(bf16x8, fb2);

    accn[0][0] = __builtin_amdgcn_mfma_f32_16x16x32_bf16(aO, b0, accn[0][0], 0, 0, 0);
    accn[0][1] = __builtin_amdgcn_mfma_f32_16x16x32_bf16(aO, b1, accn[0][1], 0, 0, 0);
    accn[0][2] = __builtin_amdgcn_mfma_f32_16x16x32_bf16(aO, b2, accn[0][2], 0, 0, 0);
    accn[1][0] = __builtin_amdgcn_mfma_f32_16x16x32_bf16(aN, b0, accn[1][0], 0, 0, 0);
    accn[1][1] = __builtin_amdgcn_mfma_f32_16x16x32_bf16(aN, b1, accn[1][1], 0, 0, 0);
    accn[1][2] = __builtin_amdgcn_mfma_f32_16x16x32_bf16(aN, b2, accn[1][2], 0, 0, 0);
    accn[2][0] = __builtin_amdgcn_mfma_f32_16x16x32_bf16(aA, b0, accn[2][0], 0, 0, 0);
    accn[2][1] = __builtin_amdgcn_mfma_f32_16x16x32_bf16(aA, b1, accn[2][1], 0, 0, 0);
    accn[2][2] = __builtin_amdgcn_mfma_f32_16x16x32_bf16(aA, b2, accn[2][2], 0, 0, 0);
    accp[0][0] = __builtin_amdgcn_mfma_f32_16x16x32_bf16(apO, b0, accp[0][0], 0, 0, 0);
    accp[0][1] = __builtin_amdgcn_mfma_f32_16x16x32_bf16(apO, b1, accp[0][1], 0, 0, 0);
    accp[0][2] = __builtin_amdgcn_mfma_f32_16x16x32_bf16(apO, b2, accp[0][2], 0, 0, 0);
    accp[1][0] = __builtin_amdgcn_mfma_f32_16x16x32_bf16(apA, b0, accp[1][0], 0, 0, 0);
    accp[1][1] = __builtin_amdgcn_mfma_f32_16x16x32_bf16(apA, b1, accp[1][1], 0, 0, 0);
    accp[1][2] = __builtin_amdgcn_mfma_f32_16x16x32_bf16(apA, b2, accp[1][2], 0, 0, 0);
}

// ---------------- mega: local t-fused (x<8) + globalrel (8..11) + contrastive (12..14)
// R10 structure, NO swizzle (identity block mapping) — isolating the swizzle A/B.
__global__ __launch_bounds__(256) void k_mega(const float* __restrict__ img,
                                              const float* __restrict__ sent,
                                              const float* __restrict__ comp,
                                              const float* __restrict__ obj,
                                              const float* __restrict__ attr,
                                              const float* __restrict__ nobj,
                                              const float* __restrict__ nattrn,
                                              const float* __restrict__ nattra,
                                              const float* __restrict__ rel,
                                              const float* __restrict__ nrel,
                                              const int*   __restrict__ relidx,
                                              const __bf16* __restrict__ wsf,
                                              float* __restrict__ ws) {
    const int x = blockIdx.x, y = blockIdx.y;
    const int tid = threadIdx.x;

    __shared__ float X[3][64][44];
    __shared__ float As[16][68];
    __shared__ float Bs[16][68];
    __shared__ float comm[8];

    if (x < 8) {
        // ======== t-fused local_loss: p = x, b = y; 4 waves = 4 K-quarters ====
        const int p = x, b = y;
        const int kh = tid >> 6;
        const int lane = tid & 63;
        const int lrow = lane & 15;
        const int kgq = lane >> 4;
        const int ksbase = kh * 8;

        const float* posO = obj    + ((size_t)b * PP + p) * DD + kgq * 8;
        const float* posA = attr   + ((size_t)b * PP + p) * DD + kgq * 8;
        const float* negO = nobj   + ((size_t)(b * PP + p) * NNEG + lrow) * DD + kgq * 8;
        const float* negN = nattrn + ((size_t)(b * PP + p) * NNEG + lrow) * DD + kgq * 8;
        const float* negA = nattra + ((size_t)(b * PP + p) * NNEG + lrow) * DD + kgq * 8;
        const __bf16* wfb = wsf + (size_t)b * WSF_PER_B + (size_t)lane * 8;

        f32x4 accn[3][3], accp[2][3];
#pragma unroll
        for (int t = 0; t < 3; ++t)
#pragma unroll
            for (int nt = 0; nt < 3; ++nt) accn[t][nt] = (f32x4){0.f, 0.f, 0.f, 0.f};
#pragma unroll
        for (int s = 0; s < 2; ++s)
#pragma unroll
            for (int nt = 0; nt < 3; ++nt) accp[s][nt] = (f32x4){0.f, 0.f, 0.f, 0.f};

        // 2-deep rotating buffer sets, individually named.
        f32x4 nO0_0, nO1_0, nN0_0, nN1_0, nA0_0, nA1_0, pO0_0, pO1_0, pA0_0, pA1_0,
              fB0_0, fB1_0, fB2_0;
        f32x4 nO0_1, nO1_1, nN0_1, nN1_1, nA0_1, nA1_1, pO0_1, pO1_1, pA0_1, pA1_1,
              fB0_1, fB1_1, fB2_1;

#define ISSUE(KS, B)                                                                    \
    {                                                                                   \
        const float* nO_ = negO + (ksbase + (KS)) * 32;                                 \
        const float* nN_ = negN + (ksbase + (KS)) * 32;                                 \
        const float* nA_ = negA + (ksbase + (KS)) * 32;                                 \
        const float* pO_ = posO + (ksbase + (KS)) * 32;                                 \
        const float* pA_ = posA + (ksbase + (KS)) * 32;                                 \
        const __bf16* g0_ = wfb + (size_t)(0 * 32 + ksbase + (KS)) * 512;               \
        const __bf16* g1_ = wfb + (size_t)(1 * 32 + ksbase + (KS)) * 512;               \
        const __bf16* g2_ = wfb + (size_t)(2 * 32 + ksbase + (KS)) * 512;               \
        asm volatile("global_load_dwordx4 %0, %1, off" : "=v"(nO0_##B) : "v"(nO_));     \
        asm volatile("global_load_dwordx4 %0, %1, off offset:16"                        \
                     : "=v"(nO1_##B) : "v"(nO_));                                       \
        asm volatile("global_load_dwordx4 %0, %1, off" : "=v"(nN0_##B) : "v"(nN_));     \
        asm volatile("global_load_dwordx4 %0, %1, off offset:16"                        \
                     : "=v"(nN1_##B) : "v"(nN_));                                       \
        asm volatile("global_load_dwordx4 %0, %1, off" : "=v"(nA0_##B) : "v"(nA_));     \
        asm volatile("global_load_dwordx4 %0, %1, off offset:16"                        \
                     : "=v"(nA1_##B) : "v"(nA_));                                       \
        asm volatile("global_load_dwordx4 %0, %1, off" : "=v"(pO0_##B) : "v"(pO_));     \
        asm volatile("global_load_dwordx4 %0, %1, off offset:16"                        \
                     : "=v"(pO1_##B) : "v"(pO_));                                       \
        asm volatile("global_load_dwordx4 %0, %1, off" : "=v"(pA0_##B) : "v"(pA_));     \
        asm volatile("global_load_dwordx4 %0, %1, off offset:16"                        \
                     : "=v"(pA1_##B) : "v"(pA_));                                       \
        asm volatile("global_load_dwordx4 %0, %1, off" : "=v"(fB0_##B) : "v"(g0_));     \
        asm volatile("global_load_dwordx4 %0, %1, off" : "=v"(fB1_##B) : "v"(g1_));     \
        asm volatile("global_load_dwordx4 %0, %1, off" : "=v"(fB2_##B) : "v"(g2_));     \
    }

#define WAITV(N)                                          \
    asm volatile("s_waitcnt vmcnt(" #N ")" ::: "memory"); \
    __builtin_amdgcn_sched_barrier(0);

#define COMPUTE(B) compute_full(nO0_##B, nO1_##B, nN0_##B, nN1_##B, nA0_##B, nA1_##B,   \
                                pO0_##B, pO1_##B, pA0_##B, pA1_##B,                     \
                                fB0_##B, fB1_##B, fB2_##B, accn, accp);

        WAITV(0)
        ISSUE(0, 0)
        ISSUE(1, 1) WAITV(13) COMPUTE(0)
        ISSUE(2, 0) WAITV(13) COMPUTE(1)
        ISSUE(3, 1) WAITV(13) COMPUTE(0)
        ISSUE(4, 0) WAITV(13) COMPUTE(1)
        ISSUE(5, 1) WAITV(13) COMPUTE(0)
        ISSUE(6, 0) WAITV(13) COMPUTE(1)
        ISSUE(7, 1) WAITV(13) COMPUTE(0)
        WAITV(0)  COMPUTE(1)

#undef ISSUE
#undef WAITV
#undef COMPUTE

        // cross-quarter combine: kh=1..3 publish 42 floats/lane, kh=0 sums.
        if (kh != 0) {
#pragma unroll
            for (int t = 0; t < 3; ++t)
#pragma unroll
                for (int nt = 0; nt < 3; ++nt) {
                    X[kh - 1][lane][t * 12 + nt * 4 + 0] = accn[t][nt][0];
                    X[kh - 1][lane][t * 12 + nt * 4 + 1] = accn[t][nt][1];
                    X[kh - 1][lane][t * 12 + nt * 4 + 2] = accn[t][nt][2];
                    X[kh - 1][lane][t * 12 + nt * 4 + 3] = accn[t][nt][3];
                }
#pragma unroll
            for (int s = 0; s < 2; ++s)
#pragma unroll
                for (int nt = 0; nt < 3; ++nt)
                    X[kh - 1][lane][36 + s * 3 + nt] = accp[s][nt][0];
        }
        __syncthreads();
        if (kh == 0) {
#pragma unroll
            for (int q = 0; q < 3; ++q) {
#pragma unroll
                for (int t = 0; t < 3; ++t)
#pragma unroll
                    for (int nt = 0; nt < 3; ++nt) {
                        accn[t][nt][0] += X[q][lane][t * 12 + nt * 4 + 0];
                        accn[t][nt][1] += X[q][lane][t * 12 + nt * 4 + 1];
                        accn[t][nt][2] += X[q][lane][t * 12 + nt * 4 + 2];
                        accn[t][nt][3] += X[q][lane][t * 12 + nt * 4 + 3];
                    }
#pragma unroll
                for (int s = 0; s < 2; ++s)
#pragma unroll
                    for (int nt = 0; nt < 3; ++nt)
                        accp[s][nt][0] += X[q][lane][36 + s * 3 + nt];
            }

            // row-max over the 16 negs per (t, nt)
            float mt[3][3];
#pragma unroll
            for (int t = 0; t < 3; ++t)
#pragma unroll
                for (int nt = 0; nt < 3; ++nt) {
                    f32x4 a = accn[t][nt];
                    float m = fmaxf(fmaxf(a[0], a[1]), fmaxf(a[2], a[3]));
                    m = fmaxf(m, __shfl_xor(m, 16));
                    m = fmaxf(m, __shfl_xor(m, 32));
                    mt[t][nt] = m;
                }
            float s0[3], s1[3];
#pragma unroll
            for (int nt = 0; nt < 3; ++nt) {
                s0[nt] = accp[0][nt][0];
                s1[nt] = accp[1][nt][0];
            }

            float mx0 = -1e30f, mx1 = -1e30f;
#pragma unroll
            for (int nt = 0; nt < 3; ++nt)
                if (nt * 16 + lrow < RR) {
                    mx0 = fmaxf(mx0, s0[nt]);
                    mx1 = fmaxf(mx1, s1[nt]);
                }
#pragma unroll
            for (int off = 1; off < 16; off <<= 1) {
                mx0 = fmaxf(mx0, __shfl_xor(mx0, off));
                mx1 = fmaxf(mx1, __shfl_xor(mx1, off));
            }
            float den0 = 0.f, num0 = 0.f, den1 = 0.f, num1 = 0.f;
#pragma unroll
            for (int nt = 0; nt < 3; ++nt)
                if (nt * 16 + lrow < RR) {
                    float e0 = __expf(s0[nt] - mx0);
                    den0 += e0;
                    num0 += e0 * fmaxf(mt[0][nt] - s0[nt], 0.0f);
                    float e1 = __expf(s1[nt] - mx1);
                    den1 += e1;
                    num1 += e1 * (fmaxf(mt[1][nt] - s1[nt], 0.0f) +
                                  fmaxf(mt[2][nt] - s1[nt], 0.0f));
                }
#pragma unroll
            for (int off = 1; off < 16; off <<= 1) {
                den0 += __shfl_xor(den0, off);
                num0 += __shfl_xor(num0, off);
                den1 += __shfl_xor(den1, off);
                num1 += __shfl_xor(num1, off);
            }
            if (lane == 0) {
                atomicAdd(&ws[0], num0 / den0);
                atomicAdd(&ws[1], num1 / den1);
            }
        }
    } else if (x < 12) {
        // ======== global_loss(rel): p = x-8, b = y; 4 waves x 4 negs ========
        const int p = x - 8, b = y;
        const int wv = tid >> 6, lane = tid & 63;
        const float* a = img + (size_t)b * DD;
        float4 ir[4];
#pragma unroll
        for (int k = 0; k < 4; ++k)
            ir[k] = *reinterpret_cast<const float4*>(a + lane * 4 + k * 256);

        auto dotv = [&](const float* __restrict__ v) -> float {
            float acc = 0.0f;
#pragma unroll
            for (int k = 0; k < 4; ++k) {
                float4 w = *reinterpret_cast<const float4*>(v + lane * 4 + k * 256);
                acc += ir[k].x * w.x + ir[k].y * w.y + ir[k].z * w.z + ir[k].w * w.w;
            }
#pragma unroll
            for (int off = 32; off > 0; off >>= 1) acc += __shfl_xor(acc, off);
            return acc;
        };

        if (wv == 0) {
            float pos = dotv(rel + ((size_t)b * PRR + p) * DD);
            if (lane == 0) comm[4] = pos;
        }
        const float* nb = nrel + ((size_t)b * PRR + p) * NNEG * DD;
        float m = -1e30f;
#pragma unroll
        for (int j = 0; j < 4; ++j)
            m = fmaxf(m, dotv(nb + (size_t)(wv * 4 + j) * DD));
        if (lane == 0) comm[wv] = m;
        __syncthreads();
        if (tid == 0) {
            float mx = fmaxf(fmaxf(comm[0], comm[1]), fmaxf(comm[2], comm[3]));
            atomicAdd(&ws[2], fmaxf(mx - comm[4], 0.0f));
        }
    } else {
        // ======== contrastive: t = x-12; y<64 => 16x16 tile (y>>3, y&7) =====
        if (y >= 64) return;
        const int t = x - 12;
        const int i0 = (y >> 3) * 16, j0 = (y & 7) * 16;
        const int ty = tid >> 4, tx = tid & 15;

        const int j_row = j0 + ty;
        const float* brow;
        if (t == 0)      brow = sent + (size_t)j_row * DD;
        else if (t == 1) brow = comp + (size_t)j_row * DD;
        else             brow = rel + ((size_t)j_row * PRR + relidx[j_row]) * DD;
        const float* arow = img + (size_t)(i0 + ty) * DD;

        float acc = 0.0f;
        for (int kc = 0; kc < DD; kc += 64) {
            __syncthreads();
            float4 va = *reinterpret_cast<const float4*>(arow + kc + tx * 4);
            float4 vb = *reinterpret_cast<const float4*>(brow + kc + tx * 4);
            *reinterpret_cast<float4*>(&As[ty][tx * 4]) = va;
            *reinterpret_cast<float4*>(&Bs[ty][tx * 4]) = vb;
            __syncthreads();
#pragma unroll 8
            for (int d = 0; d < 64; ++d)
                acc += As[ty][d] * Bs[tx][d];
        }

        const int i = i0 + ty, j = j0 + tx;
        const float diag_i = ws[WS_DIAG + t * BB + i];
        const float diag_j = ws[WS_DIAG + t * BB + j];
        float contrib = 0.0f;
        if (i != j) {
            contrib = fmaxf(acc - diag_i, 0.0f);             // cost_s
            if (t < 2) contrib += fmaxf(acc - diag_j, 0.0f); // cost_im (not for rel)
        }
#pragma unroll
        for (int off = 32; off > 0; off >>= 1) contrib += __shfl_down(contrib, off);
        if ((tid & 63) == 0) comm[tid >> 6] = contrib;
        __syncthreads();
        if (tid == 0) {
            const int slot = (t == 0) ? 4 : (t == 1) ? 3 : 2;  // sent/comp/rel
            atomicAdd(&ws[slot], comm[0] + comm[1] + comm[2] + comm[3]);
        }
    }
}

// ---------------- fallback kernels (no-wsf path) ----------------------------
__global__ __launch_bounds__(64) void k_zero(float* __restrict__ ws) {
    int t = threadIdx.x;
    if (t < 8) ws[t] = 0.0f;
}

__global__ __launch_bounds__(64) void k_diag(const float* __restrict__ img,
                                             const float* __restrict__ sent,
                                             const float* __restrict__ comp,
                                             const float* __restrict__ rel,
                                             const int*   __restrict__ relidx,
                                             float* __restrict__ ws) {
    const int i = blockIdx.x, t = blockIdx.y, lane = threadIdx.x;
    const float* x;
    if (t == 0)      x = sent + (size_t)i * DD;
    else if (t == 1) x = comp + (size_t)i * DD;
    else             x = rel + ((size_t)i * PRR + relidx[i]) * DD;
    const float* a = img + (size_t)i * DD;
    float acc = 0.0f;
#pragma unroll
    for (int k = 0; k < 4; ++k) {
        float4 va = *reinterpret_cast<const float4*>(a + lane * 4 + k * 256);
        float4 vb = *reinterpret_cast<const float4*>(x + lane * 4 + k * 256);
        acc += va.x * vb.x + va.y * vb.y + va.z * vb.z + va.w * vb.w;
    }
#pragma unroll
    for (int off = 32; off > 0; off >>= 1) acc += __shfl_down(acc, off);
    if (lane == 0) ws[WS_DIAG + t * BB + i] = acc;
}

__global__ __launch_bounds__(256) void k_contrastive(const float* __restrict__ img,
                                                     const float* __restrict__ sent,
                                                     const float* __restrict__ comp,
                                                     const float* __restrict__ rel,
                                                     const int*   __restrict__ relidx,
                                                     float* __restrict__ ws) {
    const int t  = blockIdx.z;
    const int i0 = blockIdx.y * 16, j0 = blockIdx.x * 16;
    const int tid = threadIdx.x, ty = tid >> 4, tx = tid & 15;
    __shared__ float As[16][68];
    __shared__ float Bs[16][68];
    __shared__ float red[4];

    const int j_row = j0 + ty;
    const float* brow;
    if (t == 0)      brow = sent + (size_t)j_row * DD;
    else if (t == 1) brow = comp + (size_t)j_row * DD;
    else             brow = rel + ((size_t)j_row * PRR + relidx[j_row]) * DD;
    const float* arow = img + (size_t)(i0 + ty) * DD;

    float acc = 0.0f;
    for (int kc = 0; kc < DD; kc += 64) {
        __syncthreads();
        float4 va = *reinterpret_cast<const float4*>(arow + kc + tx * 4);
        float4 vb = *reinterpret_cast<const float4*>(brow + kc + tx * 4);
        *reinterpret_cast<float4*>(&As[ty][tx * 4]) = va;
        *reinterpret_cast<float4*>(&Bs[ty][tx * 4]) = vb;
        __syncthreads();
#pragma unroll 8
        for (int d = 0; d < 64; ++d)
            acc += As[ty][d] * Bs[tx][d];
    }

    const int i = i0 + ty, j = j0 + tx;
    const float diag_i = ws[WS_DIAG + t * BB + i];
    const float diag_j = ws[WS_DIAG + t * BB + j];
    float contrib = 0.0f;
    if (i != j) {
        contrib = fmaxf(acc - diag_i, 0.0f);
        if (t < 2) contrib += fmaxf(acc - diag_j, 0.0f);
    }
#pragma unroll
    for (int off = 32; off > 0; off >>= 1) contrib += __shfl_down(contrib, off);
    if ((tid & 63) == 0) red[tid >> 6] = contrib;
    __syncthreads();
    if (tid == 0) {
        const int slot = (t == 0) ? 4 : (t == 1) ? 3 : 2;
        atomicAdd(&ws[slot], red[0] + red[1] + red[2] + red[3]);
    }
}

__global__ __launch_bounds__(64) void k_globalrel(const float* __restrict__ img,
                                                  const float* __restrict__ rel,
                                                  const float* __restrict__ negrel,
                                                  float* __restrict__ ws) {
    const int blk = blockIdx.x, b = blk >> 2, p = blk & 3;
    const int lane = threadIdx.x;
    const float* a = img + (size_t)b * DD;
    float4 ir[4];
#pragma unroll
    for (int k = 0; k < 4; ++k)
        ir[k] = *reinterpret_cast<const float4*>(a + lane * 4 + k * 256);

    auto dotv = [&](const float* __restrict__ v) -> float {
        float acc = 0.0f;
#pragma unroll
        for (int k = 0; k < 4; ++k) {
            float4 w = *reinterpret_cast<const float4*>(v + lane * 4 + k * 256);
            acc += ir[k].x * w.x + ir[k].y * w.y + ir[k].z * w.z + ir[k].w * w.w;
        }
#pragma unroll
        for (int off = 32; off > 0; off >>= 1) acc += __shfl_xor(acc, off);
        return acc;
    };

    float pos = dotv(rel + ((size_t)b * PRR + p) * DD);
    float mx = -1e30f;
    const float* nb = negrel + ((size_t)b * PRR + p) * NNEG * DD;
    for (int n = 0; n < NNEG; ++n) mx = fmaxf(mx, dotv(nb + (size_t)n * DD));
    if (lane == 0) atomicAdd(&ws[2], fmaxf(mx - pos, 0.0f));
}

__global__ __launch_bounds__(256) void k_local6f(const float* __restrict__ feat,
                                                 const float* __restrict__ obj,
                                                 const float* __restrict__ attr,
                                                 const float* __restrict__ nobj,
                                                 const float* __restrict__ nattrn,
                                                 const float* __restrict__ nattra,
                                                 float* __restrict__ ws) {
    const int t = blockIdx.x;
    const int b = blockIdx.y;
    const int p = blockIdx.z;
    const int tid = threadIdx.x;
    const int kh = tid >> 6;
    const int lane = tid & 63;
    const int lrow = lane & 15;
    const int kgq = lane >> 4;
    const int ksbase = kh * 8;

    const float* pos = (t == 0) ? obj : attr;
    const float* neg = (t == 0) ? nobj : (t == 1) ? nattrn : nattra;
    const float* posb = pos + ((size_t)b * PP + p) * DD + kgq * 8;
    const float* negb = neg + ((size_t)(b * PP + p) * NNEG + lrow) * DD + kgq * 8;
    const float* fb   = feat + (size_t)b * RR * DD;

    f32x4 accn[3], accp[3];
#pragma unroll
    for (int nt = 0; nt < 3; ++nt) {
        accn[nt] = (f32x4){0.f, 0.f, 0.f, 0.f};
        accp[nt] = (f32x4){0.f, 0.f, 0.f, 0.f};
    }

    for (int ksl = 0; ksl < 8; ++ksl) {
        const int ks = ksbase + ksl;
        const float* np = negb + ks * 32;
        float4 n0 = *reinterpret_cast<const float4*>(np);
        float4 n1 = *reinterpret_cast<const float4*>(np + 4);
        const float* pq = posb + ks * 32;
        float4 p0 = *reinterpret_cast<const float4*>(pq);
        float4 p1 = *reinterpret_cast<const float4*>(pq + 4);
        bf16x8 an, ap;
        an[0] = (__bf16)n0.x; an[1] = (__bf16)n0.y; an[2] = (__bf16)n0.z; an[3] = (__bf16)n0.w;
        an[4] = (__bf16)n1.x; an[5] = (__bf16)n1.y; an[6] = (__bf16)n1.z; an[7] = (__bf16)n1.w;
        ap[0] = (__bf16)p0.x; ap[1] = (__bf16)p0.y; ap[2] = (__bf16)p0.z; ap[3] = (__bf16)p0.w;
        ap[4] = (__bf16)p1.x; ap[5] = (__bf16)p1.y; ap[6] = (__bf16)p1.z; ap[7] = (__bf16)p1.w;
#pragma unroll
        for (int nt = 0; nt < 3; ++nt) {
            bf16x8 bt;
            const int r = nt * 16 + lrow;
            if (r < RR) {
                const float* fp = fb + (size_t)r * DD + ks * 32 + kgq * 8;
                float4 v0 = *reinterpret_cast<const float4*>(fp);
                float4 v1 = *reinterpret_cast<const float4*>(fp + 4);
                bt[0] = (__bf16)v0.x; bt[1] = (__bf16)v0.y; bt[2] = (__bf16)v0.z; bt[3] = (__bf16)v0.w;
                bt[4] = (__bf16)v1.x; bt[5] = (__bf16)v1.y; bt[6] = (__bf16)v1.z; bt[7] = (__bf16)v1.w;
            } else {
#pragma unroll
                for (int j = 0; j < 8; ++j) bt[j] = (__bf16)0.0f;
            }
            accn[nt] = __builtin_amdgcn_mfma_f32_16x16x32_bf16(an, bt, accn[nt], 0, 0, 0);
            accp[nt] = __builtin_amdgcn_mfma_f32_16x16x32_bf16(ap, bt, accp[nt], 0, 0, 0);
        }
    }

    __shared__ float X[3][64][17];
    if (kh != 0) {
#pragma unroll
        for (int nt = 0; nt < 3; ++nt) {
            X[kh - 1][lane][nt * 4 + 0] = accn[nt][0];
            X[kh - 1][lane][nt * 4 + 1] = accn[nt][1];
            X[kh - 1][lane][nt * 4 + 2] = accn[nt][2];
            X[kh - 1][lane][nt * 4 + 3] = accn[nt][3];
            X[kh - 1][lane][12 + nt]    = accp[nt][0];
        }
    }
    __syncthreads();
    if (kh == 0) {
#pragma unroll
        for (int q = 0; q < 3; ++q)
#pragma unroll
            for (int nt = 0; nt < 3; ++nt) {
                accn[nt][0] += X[q][lane][nt * 4 + 0];
                accn[nt][1] += X[q][lane][nt * 4 + 1];
                accn[nt][2] += X[q][lane][nt * 4 + 2];
                accn[nt][3] += X[q][lane][nt * 4 + 3];
                accp[nt][0] += X[q][lane][12 + nt];
            }
        float s3[3], h3[3];
#pragma unroll
        for (int nt = 0; nt < 3; ++nt) {
            f32x4 a = accn[nt];
            float m = fmaxf(fmaxf(a[0], a[1]), fmaxf(a[2], a[3]));
            m = fmaxf(m, __shfl_xor(m, 16));
            m = fmaxf(m, __shfl_xor(m, 32));
            s3[nt] = accp[nt][0];
            h3[nt] = fmaxf(m - s3[nt], 0.0f);
        }
        float mx = -1e30f;
#pragma unroll
        for (int nt = 0; nt < 3; ++nt)
            if (nt * 16 + lrow < RR) mx = fmaxf(mx, s3[nt]);
#pragma unroll
        for (int off = 1; off < 16; off <<= 1) mx = fmaxf(mx, __shfl_xor(mx, off));
        float den = 0.0f, num = 0.0f;
#pragma unroll
        for (int nt = 0; nt < 3; ++nt)
            if (nt * 16 + lrow < RR) {
                float e = __expf(s3[nt] - mx);
                den += e;
                num += e * h3[nt];
            }
#pragma unroll
        for (int off = 1; off < 16; off <<= 1) {
            den += __shfl_xor(den, off);
            num += __shfl_xor(num, off);
        }
        if (lane == 0)
            atomicAdd(&ws[(t == 0) ? 0 : 1], num / den);
    }
}

__global__ __launch_bounds__(64) void k_final(const float* __restrict__ ws,
                                              float* __restrict__ out) {
    if (threadIdx.x == 0) {
        const float obj = ws[0], attr = ws[1], rel = ws[2], comp = ws[3], sent = ws[4];
        out[0] = sent + 0.5f * comp + 0.5f * rel + 0.5f * attr + 0.5f * obj;
        out[1] = obj;
        out[2] = attr;
        out[3] = rel;
        out[4] = comp;
        out[5] = sent;
    }
}

extern "C" void kernel_launch(void* const* d_in, const int* in_sizes, int n_in,
                              void* d_out, int out_size, void* d_ws, size_t ws_size,
                              hipStream_t stream) {
    const float* img    = (const float*)d_in[0];
    const float* sent   = (const float*)d_in[1];
    const float* comp   = (const float*)d_in[2];
    const float* feat   = (const float*)d_in[3];
    const float* obj    = (const float*)d_in[4];
    const float* nobj   = (const float*)d_in[5];
    const float* attr   = (const float*)d_in[6];
    const float* nattrn = (const float*)d_in[7];
    const float* nattra = (const float*)d_in[8];
    const float* rel    = (const float*)d_in[9];
    const float* nrel   = (const float*)d_in[10];
    const int*   relidx = (const int*)d_in[11];
    float* ws  = (float*)d_ws;
    float* out = (float*)d_out;
    __bf16* wsf = (__bf16*)((char*)d_ws + WSF_OFF_BYTES);

    const bool usewsf = (ws_size >= WSF_BYTES);

    if (usewsf) {
        k_prep<<<dim3(BB, 3), dim3(256), 0, stream>>>(feat, img, sent, comp, rel, relidx,
                                                      wsf, ws);
        k_mega<<<dim3(15, BB), dim3(256), 0, stream>>>(img, sent, comp, obj, attr, nobj,
                                                       nattrn, nattra, rel, nrel, relidx,
                                                       wsf, ws);
        k_final<<<dim3(1), dim3(64), 0, stream>>>(ws, out);
    } else {
        k_zero<<<dim3(1), dim3(64), 0, stream>>>(ws);
        k_diag<<<dim3(BB, 3), dim3(64), 0, stream>>>(img, sent, comp, rel, relidx, ws);
        k_contrastive<<<dim3(8, 8, 3), dim3(256), 0, stream>>>(img, sent, comp, rel, relidx, ws);
        k_globalrel<<<dim3(BB * PRR), dim3(64), 0, stream>>>(img, rel, nrel, ws);
        k_local6f<<<dim3(3, BB, PP), dim3(256), 0, stream>>>(feat, obj, attr, nobj, nattrn,
                                                             nattra, ws);
        k_final<<<dim3(1), dim3(64), 0, stream>>>(ws, out);
    }
}